// Round 4
// baseline (105.813 us; speedup 1.0000x reference)
//
#include <hip/hip_runtime.h>

#define MARGIN 0.3f
#define EPS 1e-6f

constexpr int B = 64, N = 512, D = 512;
constexpr int NIDS = 32;          // track ids in [-1, 32)

constexpr int MB_THREADS = 256;
constexpr int MB_WAVES = MB_THREADS / 64;            // 4
constexpr int ANCH_PER_WAVE = 8;                     // 2 chunks of 4, fully prefetched
constexpr int A_BLOCK = MB_WAVES * ANCH_PER_WAVE;    // 32 anchors per block
constexpr int MB_BLOCKS = (B * N) / A_BLOCK;         // 1024

// ws layout:
//   int2  desc[B*N]        (256 KB)  per-anchor {posj, negj}, posj=-1 -> skip
//   int2  hdr[B]           (512 B)   per-batch {j0, jdiff} (clamped to N-1)
//   float psum[MB_BLOCKS]  (4 KB)
//   float pcnt[MB_BLOCKS]  (4 KB)

__global__ __launch_bounds__(512) void tl_tables(const int* __restrict__ ids,
                                                 int2* __restrict__ desc,
                                                 int2* __restrict__ hdr) {
    __shared__ int s_ids[N];
    __shared__ int s_first[NIDS], s_second[NIDS];
    __shared__ int s_j0, s_jdiff, s_vcnt;
    const int t = threadIdx.x;
    const int b = blockIdx.x;

    if (t < NIDS) { s_first[t] = N; s_second[t] = N; }
    if (t == 0) { s_j0 = N; s_jdiff = N; s_vcnt = 0; }
    __syncthreads();

    const int v = ids[b * N + t];          // one id per thread (512 == N)
    s_ids[t] = v;
    // valid count via ballot (no 512-way LDS atomic contention)
    const unsigned long long m = __ballot(v >= 0);
    if ((t & 63) == 0) atomicAdd(&s_vcnt, __popcll(m));
    if (v >= 0) {
        atomicMin(&s_first[v], t);
        atomicMin(&s_j0, t);
    }
    __syncthreads();
    const int id0 = (s_j0 < N) ? s_ids[s_j0] : -2;
    if (v >= 0) {
        if (s_first[v] != t) atomicMin(&s_second[v], t);  // second occurrence
        if (v != id0) atomicMin(&s_jdiff, t);             // first valid w/ id != id0
    }
    __syncthreads();

    int2 d = make_int2(-1, -1);
    if (v >= 0 && s_vcnt >= 2) {
        // argmax of bool mask = first True
        const int posj = (s_first[v] != t) ? s_first[v] : s_second[v];
        const int negj = (v != id0) ? s_j0 : s_jdiff;
        if (posj < N && negj < N) d = make_int2(posj, negj);
    }
    desc[b * N + t] = d;
    if (t == 0) hdr[b] = make_int2(min(s_j0, N - 1), min(s_jdiff, N - 1));
}

__global__ __launch_bounds__(MB_THREADS) void tl_main(const float* __restrict__ feats,
                                                      const int2* __restrict__ desc,
                                                      const int2* __restrict__ hdr,
                                                      float* __restrict__ psum,
                                                      float* __restrict__ pcnt) {
    __shared__ int2 s_desc[A_BLOCK];
    __shared__ float s_wsum[MB_WAVES];
    __shared__ int s_wcnt[MB_WAVES];

    const int t = threadIdx.x;
    const int lane = t & 63;
    const int wave = t >> 6;

    // XCD swizzle: XCD x (blockIdx%8) owns logical blocks x*128..x*128+127,
    // i.e. 8 whole batches -> pos gathers hit the local L2.
    const int logical = ((blockIdx.x & 7) << 7) | (blockIdx.x >> 3);
    const int b = logical >> 4;                 // 16 blocks per batch
    const int seg = (logical & 15) * A_BLOCK;   // first anchor of this block
    const float* __restrict__ bf = feats + (size_t)b * N * D;

    // Cooperative coalesced load of this block's 32 descriptors -> LDS.
    if (t < A_BLOCK) s_desc[t] = desc[b * N + seg + t];

    // Register-cache the two negative-candidate rows of this batch.
    const int2 h = hdr[b];
    const float4* n0p = (const float4*)(bf + (size_t)h.x * D) + lane * 2;
    const float4* n1p = (const float4*)(bf + (size_t)h.y * D) + lane * 2;
    const float4 n0a = n0p[0], n0b = n0p[1];
    const float4 n1a = n1p[0], n1b = n1p[1];

    __syncthreads();

    float wsum = 0.0f;
    int wcnt = 0;

    #pragma unroll
    for (int c = 0; c < ANCH_PER_WAVE / 4; ++c) {
        const int base = wave * ANCH_PER_WAVE + c * 4;   // index into s_desc

        int pj[4]; bool okk[4]; bool useN0[4];
        #pragma unroll
        for (int k = 0; k < 4; ++k) {
            const int2 d = s_desc[base + k];
            okk[k] = (d.x >= 0);
            pj[k] = okk[k] ? d.x : 0;
            useN0[k] = (d.y == h.x);
        }

        // Issue all 16 independent 16B loads before any compute.
        float4 A0[4], A1[4], P0[4], P1[4];
        #pragma unroll
        for (int k = 0; k < 4; ++k) {
            const int i = seg + base + k;
            const float4* fa = (const float4*)(bf + (size_t)i * D) + lane * 2;
            const float4* fp = (const float4*)(bf + (size_t)pj[k] * D) + lane * 2;
            A0[k] = fa[0]; A1[k] = fa[1];
            P0[k] = fp[0]; P1[k] = fp[1];
        }

        #pragma unroll
        for (int k = 0; k < 4; ++k) {
            const float4 m0 = useN0[k] ? n0a : n1a;
            const float4 m1 = useN0[k] ? n0b : n1b;
            float sap = 0.0f, san = 0.0f, dd;
            dd = A0[k].x - P0[k].x + EPS; sap += dd * dd;
            dd = A0[k].y - P0[k].y + EPS; sap += dd * dd;
            dd = A0[k].z - P0[k].z + EPS; sap += dd * dd;
            dd = A0[k].w - P0[k].w + EPS; sap += dd * dd;
            dd = A1[k].x - P1[k].x + EPS; sap += dd * dd;
            dd = A1[k].y - P1[k].y + EPS; sap += dd * dd;
            dd = A1[k].z - P1[k].z + EPS; sap += dd * dd;
            dd = A1[k].w - P1[k].w + EPS; sap += dd * dd;
            dd = A0[k].x - m0.x + EPS; san += dd * dd;
            dd = A0[k].y - m0.y + EPS; san += dd * dd;
            dd = A0[k].z - m0.z + EPS; san += dd * dd;
            dd = A0[k].w - m0.w + EPS; san += dd * dd;
            dd = A1[k].x - m1.x + EPS; san += dd * dd;
            dd = A1[k].y - m1.y + EPS; san += dd * dd;
            dd = A1[k].z - m1.z + EPS; san += dd * dd;
            dd = A1[k].w - m1.w + EPS; san += dd * dd;

            #pragma unroll
            for (int off = 32; off >= 1; off >>= 1) {
                sap += __shfl_xor(sap, off);
                san += __shfl_xor(san, off);
            }
            const float per = fmaxf(sqrtf(sap) - sqrtf(san) + MARGIN, 0.0f);
            wsum += okk[k] ? per : 0.0f;
            wcnt += okk[k] ? 1 : 0;
        }
    }

    if (lane == 0) { s_wsum[wave] = wsum; s_wcnt[wave] = wcnt; }
    __syncthreads();
    if (t == 0) {
        float s = 0.0f; int c = 0;
        #pragma unroll
        for (int w = 0; w < MB_WAVES; ++w) { s += s_wsum[w]; c += s_wcnt[w]; }
        psum[blockIdx.x] = s;
        pcnt[blockIdx.x] = (float)c;
    }
}

__global__ __launch_bounds__(256) void tl_finalize(const float* __restrict__ psum,
                                                   const float* __restrict__ pcnt,
                                                   float* __restrict__ out) {
    __shared__ float s_s[4], s_c[4];
    const int t = threadIdx.x;
    float s = 0.0f, c = 0.0f;
    for (int k = t; k < MB_BLOCKS; k += 256) { s += psum[k]; c += pcnt[k]; }
    #pragma unroll
    for (int off = 32; off >= 1; off >>= 1) {
        s += __shfl_xor(s, off);
        c += __shfl_xor(c, off);
    }
    if ((t & 63) == 0) { s_s[t >> 6] = s; s_c[t >> 6] = c; }
    __syncthreads();
    if (t == 0) {
        const float S = s_s[0] + s_s[1] + s_s[2] + s_s[3];
        const float C = s_c[0] + s_c[1] + s_c[2] + s_c[3];
        const float loss = (C > 0.0f) ? (S / C) : 0.0f;
        out[0] = loss;   // tracking_loss = triplet + id(=0)
        out[1] = loss;   // loss_triplet
        out[2] = 0.0f;   // loss_id
    }
}

extern "C" void kernel_launch(void* const* d_in, const int* in_sizes, int n_in,
                              void* d_out, int out_size, void* d_ws, size_t ws_size,
                              hipStream_t stream) {
    const float* feats = (const float*)d_in[0];  // (B,N,D) fp32
    const int* ids = (const int*)d_in[1];        // (B,N) int32
    float* out = (float*)d_out;                  // 3 fp32 scalars

    char* ws = (char*)d_ws;
    int2* desc = (int2*)ws;                                   // 256 KB
    int2* hdr = (int2*)(ws + sizeof(int2) * B * N);           // 512 B
    float* psum = (float*)(ws + sizeof(int2) * (B * N + B));  // 4 KB
    float* pcnt = psum + MB_BLOCKS;                           // 4 KB

    tl_tables<<<B, 512, 0, stream>>>(ids, desc, hdr);
    tl_main<<<MB_BLOCKS, MB_THREADS, 0, stream>>>(feats, desc, hdr, psum, pcnt);
    tl_finalize<<<1, 256, 0, stream>>>(psum, pcnt, out);
}

// Round 5
// 103.307 us; speedup vs baseline: 1.0243x; 1.0243x over previous
//
#include <hip/hip_runtime.h>

#define MARGIN 0.3f
#define EPS 1e-6f

constexpr int B = 64, N = 512, D = 512;
constexpr int NIDS = 32;          // track ids in [-1, 32)

constexpr int MB_THREADS = 512;                      // 8 waves; also == N for table build
constexpr int MB_WAVES = MB_THREADS / 64;            // 8
constexpr int ANCH_PER_WAVE = 8;                     // 2 chunks of 4, fully prefetched
constexpr int A_BLOCK = MB_WAVES * ANCH_PER_WAVE;    // 64 anchors per block
constexpr int MB_BLOCKS = (B * N) / A_BLOCK;         // 512 (8 blocks per batch)

// ws layout: float psum[512]; float pcnt[512]  (4 KB)

__global__ __launch_bounds__(MB_THREADS) void tl_main(const float* __restrict__ feats,
                                                      const int* __restrict__ ids,
                                                      float* __restrict__ psum,
                                                      float* __restrict__ pcnt) {
    __shared__ int s_ids[N];
    __shared__ int s_first[NIDS], s_second[NIDS];
    __shared__ int s_j0, s_jdiff, s_vcnt;
    __shared__ float s_wsum[MB_WAVES];
    __shared__ int s_wcnt[MB_WAVES];

    const int t = threadIdx.x;
    const int lane = t & 63;
    const int wave = t >> 6;

    // XCD swizzle: XCD x (= blockIdx%8) owns logical blocks x*64..x*64+63,
    // i.e. 8 whole batches -> pos/neg gathers stay in the local L2's hot set.
    const int logical = ((blockIdx.x & 7) << 6) | (blockIdx.x >> 3);
    const int b = logical >> 3;                  // 8 blocks per batch
    const int seg = (logical & 7) * A_BLOCK;     // first anchor of this block
    const float* __restrict__ bf = feats + (size_t)b * N * D;

    // ---- per-batch table build (8x redundant across blocks; measured-cheap) ----
    if (t < NIDS) { s_first[t] = N; s_second[t] = N; }
    if (t == 0) { s_j0 = N; s_jdiff = N; s_vcnt = 0; }
    __syncthreads();

    const int v = ids[b * N + t];                // one id per thread (MB_THREADS == N)
    s_ids[t] = v;
    const unsigned long long m = __ballot(v >= 0);
    if (lane == 0) atomicAdd(&s_vcnt, __popcll(m));
    if (v >= 0) {
        atomicMin(&s_first[v], t);
        atomicMin(&s_j0, t);
    }
    __syncthreads();
    const int id0 = (s_j0 < N) ? s_ids[s_j0] : -2;
    if (v >= 0) {
        if (s_first[v] != t) atomicMin(&s_second[v], t);  // second occurrence
        if (v != id0) atomicMin(&s_jdiff, t);             // first valid w/ id != id0
    }
    __syncthreads();

    const int vcnt = s_vcnt;
    const int j0 = min(s_j0, N - 1), jdiff = min(s_jdiff, N - 1);

    // Register-cache the two negative-candidate rows of this batch.
    const float4* n0p = (const float4*)(bf + (size_t)j0 * D) + lane * 2;
    const float4* n1p = (const float4*)(bf + (size_t)jdiff * D) + lane * 2;
    const float4 n0a = n0p[0], n0b = n0p[1];
    const float4 n1a = n1p[0], n1b = n1p[1];

    float wsum = 0.0f;
    int wcnt = 0;

    #pragma unroll
    for (int c = 0; c < ANCH_PER_WAVE / 4; ++c) {
        const int base = seg + wave * ANCH_PER_WAVE + c * 4;

        int pj[4]; bool okk[4]; bool useN0[4];
        #pragma unroll
        for (int k = 0; k < 4; ++k) {
            const int i = base + k;
            const int vi = s_ids[i];
            bool ok = (vi >= 0) && (vcnt >= 2);
            int posj = 0, negj = 0;
            if (ok) {
                // argmax of bool mask = first True
                posj = (s_first[vi] != i) ? s_first[vi] : s_second[vi];
                negj = (vi != id0) ? s_j0 : s_jdiff;
                ok = (posj < N) && (negj < N);
            }
            okk[k] = ok;
            pj[k] = ok ? posj : 0;
            useN0[k] = (negj == s_j0);
        }

        // Issue all 16 independent 16B loads before any compute.
        float4 A0[4], A1[4], P0[4], P1[4];
        #pragma unroll
        for (int k = 0; k < 4; ++k) {
            const int i = base + k;
            const float4* fa = (const float4*)(bf + (size_t)i * D) + lane * 2;
            const float4* fp = (const float4*)(bf + (size_t)pj[k] * D) + lane * 2;
            A0[k] = fa[0]; A1[k] = fa[1];
            P0[k] = fp[0]; P1[k] = fp[1];
        }

        #pragma unroll
        for (int k = 0; k < 4; ++k) {
            const float4 m0 = useN0[k] ? n0a : n1a;
            const float4 m1 = useN0[k] ? n0b : n1b;
            float sap = 0.0f, san = 0.0f, dd;
            dd = A0[k].x - P0[k].x + EPS; sap += dd * dd;
            dd = A0[k].y - P0[k].y + EPS; sap += dd * dd;
            dd = A0[k].z - P0[k].z + EPS; sap += dd * dd;
            dd = A0[k].w - P0[k].w + EPS; sap += dd * dd;
            dd = A1[k].x - P1[k].x + EPS; sap += dd * dd;
            dd = A1[k].y - P1[k].y + EPS; sap += dd * dd;
            dd = A1[k].z - P1[k].z + EPS; sap += dd * dd;
            dd = A1[k].w - P1[k].w + EPS; sap += dd * dd;
            dd = A0[k].x - m0.x + EPS; san += dd * dd;
            dd = A0[k].y - m0.y + EPS; san += dd * dd;
            dd = A0[k].z - m0.z + EPS; san += dd * dd;
            dd = A0[k].w - m0.w + EPS; san += dd * dd;
            dd = A1[k].x - m1.x + EPS; san += dd * dd;
            dd = A1[k].y - m1.y + EPS; san += dd * dd;
            dd = A1[k].z - m1.z + EPS; san += dd * dd;
            dd = A1[k].w - m1.w + EPS; san += dd * dd;

            #pragma unroll
            for (int off = 32; off >= 1; off >>= 1) {
                sap += __shfl_xor(sap, off);
                san += __shfl_xor(san, off);
            }
            const float per = fmaxf(sqrtf(sap) - sqrtf(san) + MARGIN, 0.0f);
            wsum += okk[k] ? per : 0.0f;
            wcnt += okk[k] ? 1 : 0;
        }
    }

    if (lane == 0) { s_wsum[wave] = wsum; s_wcnt[wave] = wcnt; }
    __syncthreads();
    if (t == 0) {
        float s = 0.0f; int c = 0;
        #pragma unroll
        for (int w = 0; w < MB_WAVES; ++w) { s += s_wsum[w]; c += s_wcnt[w]; }
        psum[blockIdx.x] = s;
        pcnt[blockIdx.x] = (float)c;
    }
}

__global__ __launch_bounds__(256) void tl_finalize(const float* __restrict__ psum,
                                                   const float* __restrict__ pcnt,
                                                   float* __restrict__ out) {
    __shared__ float s_s[4], s_c[4];
    const int t = threadIdx.x;
    float s = 0.0f, c = 0.0f;
    for (int k = t; k < MB_BLOCKS; k += 256) { s += psum[k]; c += pcnt[k]; }
    #pragma unroll
    for (int off = 32; off >= 1; off >>= 1) {
        s += __shfl_xor(s, off);
        c += __shfl_xor(c, off);
    }
    if ((t & 63) == 0) { s_s[t >> 6] = s; s_c[t >> 6] = c; }
    __syncthreads();
    if (t == 0) {
        const float S = s_s[0] + s_s[1] + s_s[2] + s_s[3];
        const float C = s_c[0] + s_c[1] + s_c[2] + s_c[3];
        const float loss = (C > 0.0f) ? (S / C) : 0.0f;
        out[0] = loss;   // tracking_loss = triplet + id(=0)
        out[1] = loss;   // loss_triplet
        out[2] = 0.0f;   // loss_id
    }
}

extern "C" void kernel_launch(void* const* d_in, const int* in_sizes, int n_in,
                              void* d_out, int out_size, void* d_ws, size_t ws_size,
                              hipStream_t stream) {
    const float* feats = (const float*)d_in[0];  // (B,N,D) fp32
    const int* ids = (const int*)d_in[1];        // (B,N) int32
    float* out = (float*)d_out;                  // 3 fp32 scalars

    float* psum = (float*)d_ws;                  // 512 floats
    float* pcnt = psum + MB_BLOCKS;              // 512 floats

    tl_main<<<MB_BLOCKS, MB_THREADS, 0, stream>>>(feats, ids, psum, pcnt);
    tl_finalize<<<1, 256, 0, stream>>>(psum, pcnt, out);
}